// Round 2
// baseline (282.662 us; speedup 1.0000x reference)
//
#include <hip/hip_runtime.h>
#include <stdint.h>

typedef unsigned long long u64;
typedef float v2 __attribute__((ext_vector_type(2)));

#define THRESH_F 5e-5f
#define BB 128
#define HH 384
#define WW_ 384
#define WPR 6                        // u64 words per 384-pixel row
#define IMG_WORDS (HH*WPR)           // 2304
#define ROWS_TOTAL (BB*HH)           // 49152
#define WORDS_TOTAL (ROWS_TOTAL*WPR) // 294912
#define OH 378
#define OW 378
#define PIX (BB*HH*WW_)              // 18874368
#define COVN (49.0f/48.0f)

// ---------------- K1: binarize Y -> bitmask via wave ballot ----------------
__global__ void k_binarize(const float* __restrict__ Y, u64* __restrict__ bits) {
    int idx = blockIdx.x * 256 + threadIdx.x;         // grid exact: PIX/256
    float y = Y[idx];
    u64 bal = __ballot(y > THRESH_F);
    if ((threadIdx.x & 63) == 0) bits[idx >> 6] = bal;
}

// ---------------- K2: fused morphology, one block per image, LDS-resident --
// erode3 -> dilate_h15 -> dilate_v15 -> erode_h14 -> erode_v14
__global__ void __launch_bounds__(256) k_morph(const u64* __restrict__ gin_all,
                                               u64* __restrict__ gout_all) {
    __shared__ u64 A[IMG_WORDS];
    __shared__ u64 Bf[IMG_WORDS];
    const int b = blockIdx.x;
    const u64* gin = gin_all + (size_t)b * IMG_WORDS;
    u64* gout = gout_all + (size_t)b * IMG_WORDS;
    const int t = threadIdx.x;

    for (int w = t; w < IMG_WORDS; w += 256) A[w] = gin[w];
    __syncthreads();

    // ---- erode3: A -> Bf (OOB = 1 for erosion) ----
    #pragma unroll
    for (int it = 0; it < 9; ++it) {
        int w = t + it * 256;
        int row = (w * 43691) >> 18;          // w/6, exact for w < 2^17
        int ww = w - row * 6;
        u64 res = ~0ull;
        int rlo = row > 0 ? row - 1 : row;
        int rhi = row < HH - 1 ? row + 1 : row;
        for (int rr = rlo; rr <= rhi; ++rr) {
            const u64* rp = &A[rr * 6];
            u64 a = ww > 0 ? rp[ww - 1] : 0ull;
            u64 bb = rp[ww];
            u64 c = ww < 5 ? rp[ww + 1] : 0ull;
            u64 l  = (bb << 1) | (ww > 0 ? (a >> 63) : 1ull);
            u64 r2 = (bb >> 1) | (ww < 5 ? (c << 63) : (1ull << 63));
            res &= bb & l & r2;
        }
        Bf[w] = res;
    }
    __syncthreads();

    // ---- dilate_h15: Bf -> A (OOB = 0) ----
    #pragma unroll
    for (int it = 0; it < 9; ++it) {
        int w = t + it * 256;
        int row = (w * 43691) >> 18;
        int ww = w - row * 6;
        const u64* rp = &Bf[row * 6];
        u64 a = ww > 0 ? rp[ww - 1] : 0ull;
        u64 bb = rp[ww];
        u64 c = ww < 5 ? rp[ww + 1] : 0ull;
        __uint128_t X = (((__uint128_t)bb) << 64) | a;
        X |= X << 1; X |= X << 2; X |= X << 4; X |= X << 8;
        __uint128_t Z = (((__uint128_t)c) << 64) | bb;
        Z |= Z >> 1; Z |= Z >> 2; Z |= Z >> 4; Z |= Z >> 8;
        A[w] = (u64)(X >> 64) | (u64)Z;
    }
    __syncthreads();

    // ---- dilate_v15: A -> Bf ----
    #pragma unroll
    for (int it = 0; it < 9; ++it) {
        int w = t + it * 256;
        int row = (w * 43691) >> 18;
        int ww = w - row * 6;
        int lo = row - 15 < 0 ? 0 : row - 15;
        int hi = row + 15 > HH - 1 ? HH - 1 : row + 15;
        u64 acc = 0ull;
        for (int rr = lo; rr <= hi; ++rr) acc |= A[rr * 6 + ww];
        Bf[w] = acc;
    }
    __syncthreads();

    // ---- erode_h14: Bf -> A (complement-dilate, OOB = 1) ----
    #pragma unroll
    for (int it = 0; it < 9; ++it) {
        int w = t + it * 256;
        int row = (w * 43691) >> 18;
        int ww = w - row * 6;
        const u64* rp = &Bf[row * 6];
        u64 a = ww > 0 ? rp[ww - 1] : ~0ull;
        u64 bb = rp[ww];
        u64 c = ww < 5 ? rp[ww + 1] : ~0ull;
        u64 na = ~a, nb = ~bb, nc = ~c;
        __uint128_t X = (((__uint128_t)nb) << 64) | na;
        X |= X << 1; X |= X << 2; X |= X << 4; X |= X << 7;
        __uint128_t Z = (((__uint128_t)nc) << 64) | nb;
        Z |= Z >> 1; Z |= Z >> 2; Z |= Z >> 4; Z |= Z >> 7;
        A[w] = ~((u64)(X >> 64) | (u64)Z);
    }
    __syncthreads();

    // ---- erode_v14: A -> global ----
    #pragma unroll
    for (int it = 0; it < 9; ++it) {
        int w = t + it * 256;
        int row = (w * 43691) >> 18;
        int ww = w - row * 6;
        int lo = row - 14 < 0 ? 0 : row - 14;
        int hi = row + 14 > HH - 1 ? HH - 1 : row + 14;
        u64 acc = ~0ull;
        for (int rr = lo; rr <= hi; ++rr) acc &= A[rr * 6 + ww];
        gout[w] = acc;
    }
}

// ---------------- K3: fused masked SSIM, CW=2 columns/thread ---------------
// grid (3, 3, 128), block 256: 64 pairs x 4 chunk-slots. Each thread: output
// columns (2p, 2p+1), 32 output rows, ring of horizontal 7-sums with STATIC
// phase indexing (row loop unrolled x7), packed float2 math, rcp division.
__global__ void __launch_bounds__(256) k_ssim(
    const float* __restrict__ Xg, const float* __restrict__ Yg,
    const float* __restrict__ drg, const u64* __restrict__ Mg,
    float* __restrict__ accum)
{
    const int tx = threadIdx.x & 63;
    const int cz = threadIdx.x >> 6;
    const int p  = blockIdx.x * 64 + tx;              // pair index
    const int chunk = blockIdx.y * 4 + cz;            // 0..11 (uniform per wave)
    const int b  = blockIdx.z;

    float lsum = 0.0f;
    if (p < 189) {
        const int j  = p * 2;
        const int i0 = chunk * 32;
        const int i1 = (i0 + 32 < OH) ? (i0 + 32) : OH;
        const int nrows = (i1 - i0) + 6;              // uniform per wave
        const float drv = drg[b];
        const float C1q = 1e-4f * drv * drv * 2401.0f;    // C1*49^2
        const float C2q = 9e-4f * drv * drv * 2401.0f;    // C2*49^2
        const float* Xp = Xg + (size_t)b * HH * WW_ + (size_t)i0 * WW_ + j;
        const float* Yp = Yg + (size_t)b * HH * WW_ + (size_t)i0 * WW_ + j;
        const int w0i = j >> 6;
        const int w1i = (w0i < WPR - 1) ? (w0i + 1) : w0i;  // clamped; garbage bits land >= bit 8
        const int sh  = j & 63;
        const u64* Mp = Mg + (size_t)b * HH * WPR + (size_t)i0 * WPR;

        v2 ring0[7], ring1[7], ring2[7], ring3[7], ring4[7];
        #pragma unroll
        for (int t = 0; t < 7; ++t) {
            ring0[t] = 0.f; ring1[t] = 0.f; ring2[t] = 0.f; ring3[t] = 0.f; ring4[t] = 0.f;
        }
        v2 s0 = 0.f, s1 = 0.f, s2 = 0.f, s3 = 0.f, s4 = 0.f;

        for (int base = 0; base < 42; base += 7) {
            if (base >= nrows) break;                 // uniform
            #pragma unroll
            for (int ph = 0; ph < 7; ++ph) {
                const int rr = base + ph;
                if (rr >= nrows) break;               // uniform
                const float* xr = Xp + rr * WW_;
                const float* yr = Yp + rr * WW_;
                v2 xa = *(const v2*)(xr);     v2 xb = *(const v2*)(xr + 2);
                v2 xc = *(const v2*)(xr + 4); v2 xd = *(const v2*)(xr + 6);
                v2 ya = *(const v2*)(yr);     v2 yb = *(const v2*)(yr + 2);
                v2 yc = *(const v2*)(yr + 4); v2 yd = *(const v2*)(yr + 6);

                const u64* mrow = Mp + rr * WPR;
                u64 mw0 = mrow[w0i];
                u64 mw1 = mrow[w1i];
                unsigned win8 = ((unsigned)(mw0 >> sh) |
                                 (unsigned)((mw1 << 1) << (63 - sh))) & 0xFFu;

                if (__builtin_expect(__any(win8 != 0xFFu), 0)) {
                    // rare slow path: apply per-pixel mask
                    float m0 = (float)( win8       & 1u);
                    float m1 = (float)((win8 >> 1) & 1u);
                    float m2 = (float)((win8 >> 2) & 1u);
                    float m3 = (float)((win8 >> 3) & 1u);
                    float m4 = (float)((win8 >> 4) & 1u);
                    float m5 = (float)((win8 >> 5) & 1u);
                    float m6 = (float)((win8 >> 6) & 1u);
                    float m7 = (float)((win8 >> 7) & 1u);
                    xa.x *= m0; xa.y *= m1; xb.x *= m2; xb.y *= m3;
                    xc.x *= m4; xc.y *= m5; xd.x *= m6; xd.y *= m7;
                    ya.x *= m0; ya.y *= m1; yb.x *= m2; yb.y *= m3;
                    yc.x *= m4; yc.y *= m5; yd.x *= m6; yd.y *= m7;
                }

                // per-pixel products (packed)
                v2 xxa = xa * xa, xxb = xb * xb, xxc = xc * xc, xxd = xd * xd;
                v2 yya = ya * ya, yyb = yb * yb, yyc = yc * yc, yyd = yd * yd;
                v2 xya = xa * ya, xyb = xb * yb, xyc = xc * yc, xyd = xd * yd;

                // horizontal 7-sums; h.y = h.x + p7 - p0
                float h;
                h = ((xa.x + xa.y) + (xb.x + xb.y)) + ((xc.x + xc.y) + xd.x);
                v2 hX  = { h, h + xd.y - xa.x };
                h = ((ya.x + ya.y) + (yb.x + yb.y)) + ((yc.x + yc.y) + yd.x);
                v2 hY  = { h, h + yd.y - ya.x };
                h = ((xxa.x + xxa.y) + (xxb.x + xxb.y)) + ((xxc.x + xxc.y) + xxd.x);
                v2 hXX = { h, h + xxd.y - xxa.x };
                h = ((yya.x + yya.y) + (yyb.x + yyb.y)) + ((yyc.x + yyc.y) + yyd.x);
                v2 hYY = { h, h + yyd.y - yya.x };
                h = ((xya.x + xya.y) + (xyb.x + xyb.y)) + ((xyc.x + xyc.y) + xyd.x);
                v2 hXY = { h, h + xyd.y - xya.x };

                // vertical slide, static ring index
                v2 o;
                o = ring0[ph]; ring0[ph] = hX;  s0 += hX  - o;
                o = ring1[ph]; ring1[ph] = hY;  s1 += hY  - o;
                o = ring2[ph]; ring2[ph] = hXX; s2 += hXX - o;
                o = ring3[ph]; ring3[ph] = hYY; s3 += hYY - o;
                o = ring4[ph]; ring4[ph] = hXY; s4 += hXY - o;

                if (rr >= 6) {
                    // folded SSIM on raw 49-sums (49^4 cancels)
                    v2 t3  = s0 * s1;
                    v2 t12 = s1 * s1 + s0 * s0;
                    v2 A1  = 2.0f * t3 + C1q;
                    v2 u   = 49.0f * s4 - t3;
                    v2 A2  = (2.0f * COVN) * u + C2q;
                    v2 B1  = t12 + C1q;
                    v2 w   = s2 + s3;
                    v2 vsum = 49.0f * w - t12;
                    v2 B2  = COVN * vsum + C2q;
                    v2 num = A1 * A2;
                    v2 den = B1 * B2;
                    float r0 = __builtin_amdgcn_rcpf(den.x);
                    float r1 = __builtin_amdgcn_rcpf(den.y);
                    lsum += num.x * r0 + num.y * r1;
                }
            }
        }
    }

    __shared__ float sm[256];
    sm[threadIdx.x] = lsum;
    __syncthreads();
    #pragma unroll
    for (int off = 128; off > 0; off >>= 1) {
        if (threadIdx.x < off) sm[threadIdx.x] += sm[threadIdx.x + off];
        __syncthreads();
    }
    if (threadIdx.x == 0) {
        int flat = (blockIdx.z * 3 + blockIdx.y) * 3 + blockIdx.x;
        atomicAdd(&accum[flat & 1023], sm[0]);
    }
}

// ---------------- K4: finalize -> 1 - sum/N (double accumulate) ------------
__global__ void k_final(const float* __restrict__ accum, float* __restrict__ out) {
    __shared__ double sm[256];
    double v = 0.0;
    for (int i = threadIdx.x; i < 1024; i += 256) v += (double)accum[i];
    sm[threadIdx.x] = v;
    __syncthreads();
    #pragma unroll
    for (int off = 128; off > 0; off >>= 1) {
        if (threadIdx.x < off) sm[threadIdx.x] += sm[threadIdx.x + off];
        __syncthreads();
    }
    if (threadIdx.x == 0) {
        out[0] = (float)(1.0 - sm[0] / 18289152.0);   // N = 128*378*378
    }
}

extern "C" void kernel_launch(void* const* d_in, const int* in_sizes, int n_in,
                              void* d_out, int out_size, void* d_ws, size_t ws_size,
                              hipStream_t stream) {
    const float* X  = (const float*)d_in[0];
    const float* Y  = (const float*)d_in[1];
    const float* dr = (const float*)d_in[2];
    float* out = (float*)d_out;

    char* ws = (char*)d_ws;
    float* accum = (float*)ws;                                   // 4 KB
    u64* bufA = (u64*)(ws + 4096);                               // 2.36 MB
    u64* bufB = (u64*)(ws + 4096 + (size_t)WORDS_TOTAL * 8);     // 2.36 MB

    hipMemsetAsync(accum, 0, 1024 * sizeof(float), stream);

    k_binarize<<<PIX / 256, 256, 0, stream>>>(Y, bufA);
    k_morph<<<BB, 256, 0, stream>>>(bufA, bufB);
    dim3 g(3, 3, 128);
    k_ssim<<<g, 256, 0, stream>>>(X, Y, dr, bufB, accum);
    k_final<<<1, 256, 0, stream>>>(accum, out);
}